// Round 8
// baseline (846.844 us; speedup 1.0000x reference)
//
#include <hip/hip_runtime.h>

#define NXN 96
#define NNODE (NXN*NXN)
#define NCW 95
#define NTHREADS 1024
#define NWAVES (NTHREADS/64)
#define MAXIT_OUT 300
#define ATOL_E 3e-4       // absolute tail bound on alpha*gamma
#define OMEGA 0.6f

__device__ __forceinline__ void dual_warp_red(double& a, double& b){
  #pragma unroll
  for (int off = 32; off > 0; off >>= 1){
    a += __shfl_down(a, off, 64);
    b += __shfl_down(b, off, 64);
  }
}

__device__ __forceinline__ double sum16_tree(const double* buf){
  double t0 = buf[0]  + buf[1],  t1 = buf[2]  + buf[3];
  double t2 = buf[4]  + buf[5],  t3 = buf[6]  + buf[7];
  double t4 = buf[8]  + buf[9],  t5 = buf[10] + buf[11];
  double t6 = buf[12] + buf[13], t7 = buf[14] + buf[15];
  double u0 = t0 + t1, u1 = t2 + t3, u2 = t4 + t5, u3 = t6 + t7;
  return (u0 + u1) + (u2 + u3);
}

// ---- level helpers (coarse levels: Dirichlet at i==0 only) ----
template<int N, int NC>
__device__ __forceinline__ float sgf(const float* sig, int ci, int cj){
  return (ci >= 0 && ci < NC && cj >= 0 && cj < NC) ? sig[cj*NC + ci] : 0.f;
}
template<int N>
__device__ __forceinline__ float vf(const float* v, int i, int j){
  return (i >= 0 && i < N && j >= 0 && j < N) ? v[j*N + i] : 0.f;
}
template<int N, int NC>
__device__ __forceinline__ float diagA(const float* sig, int i, int j){
  float s00 = sgf<N,NC>(sig,i,j),   sW  = sgf<N,NC>(sig,i-1,j);
  float sS  = sgf<N,NC>(sig,i,j-1), sWS = sgf<N,NC>(sig,i-1,j-1);
  return s00 + 3.f*sW + sS + sWS;
}
// stencil apply with value functor
template<int N, int NC, typename F>
__device__ __forceinline__ float applyA_f(const float* sig, F v, int i, int j){
  float s00 = sgf<N,NC>(sig,i,j),   sW  = sgf<N,NC>(sig,i-1,j);
  float sS  = sgf<N,NC>(sig,i,j-1), sWS = sgf<N,NC>(sig,i-1,j-1);
  return (s00 + 3.f*sW + sS + sWS)*v(i,j)
       + 0.5f*(sS  - s00)*v(i+1,j)
       + 0.5f*(sWS - sW )*v(i-1,j)
       - 0.5f*(s00 + 3.f*sW )*v(i,j+1)
       - 0.5f*(sS  + 3.f*sWS)*v(i,j-1)
       - sW*v(i-1,j+1)
       - sS*v(i+1,j-1);
}
template<int N, int NC>
__device__ __forceinline__ float applyA(const float* sig, const float* z, int i, int j){
  auto V = [&](int ii, int jj)->float{ return vf<N>(z, ii, jj); };
  return applyA_f<N,NC>(sig, V, i, j);
}
// prolongation value at fine (i,j) from coarse zc (N fine = 2*Nc)
template<int Nc>
__device__ __forceinline__ float pval(const float* zc, int i, int j){
  int ie = i & 1, je = j & 1;
  if (!ie && !je) return vf<Nc>(zc, i>>1, j>>1);
  if ( ie && !je) return 0.5f*(vf<Nc>(zc,(i-1)>>1, j>>1) + vf<Nc>(zc,(i+1)>>1, j>>1));
  if (!ie &&  je) return 0.5f*(vf<Nc>(zc, i>>1,(j-1)>>1) + vf<Nc>(zc, i>>1,(j+1)>>1));
  return 0.5f*(vf<Nc>(zc,(i+1)>>1,(j-1)>>1) + vf<Nc>(zc,(i-1)>>1,(j+1)>>1));
}

// restrict precomputed fine residual (96 level) + smooth coarse from zero
template<int Nf, int Nc, int NCc>
__device__ void rrs0(const float* dfine, const float* sigc, float* fc, float* zc, int tid){
  for (int n = tid; n < Nc*Nc; n += NTHREADS){
    int I = n % Nc, J = n / Nc;
    float v = 0.f;
    if (I != 0){
      int fi = 2*I, fj = 2*J;
      v = vf<Nf>(dfine,fi,fj)
        + 0.5f*( vf<Nf>(dfine,fi+1,fj) + vf<Nf>(dfine,fi-1,fj)
               + vf<Nf>(dfine,fi,fj+1) + vf<Nf>(dfine,fi,fj-1)
               + vf<Nf>(dfine,fi+1,fj-1) + vf<Nf>(dfine,fi-1,fj+1) );
    }
    fc[n] = v;
    zc[n] = (I == 0) ? 0.f : OMEGA * v / diagA<Nc,NCc>(sigc, I, J);
  }
}
// fused: residual(fine) -> restrict -> smooth coarse from zero
template<int Nf, int NCf, int Nc, int NCc>
__device__ void frrs(const float* sigf, const float* ff, const float* zf,
                     const float* sigc, float* fc, float* zc, int tid){
  for (int n = tid; n < Nc*Nc; n += NTHREADS){
    int I = n % Nc, J = n / Nc;
    float v = 0.f;
    if (I != 0){
      auto RS = [&](int i, int j)->float{
        if (i <= 0 || i >= Nf || j < 0 || j >= Nf) return 0.f;
        return ff[j*Nf+i] - applyA<Nf,NCf>(sigf, zf, i, j);
      };
      int fi = 2*I, fj = 2*J;
      v = RS(fi,fj)
        + 0.5f*( RS(fi+1,fj) + RS(fi-1,fj) + RS(fi,fj+1) + RS(fi,fj-1)
               + RS(fi+1,fj-1) + RS(fi-1,fj+1) );
    }
    fc[n] = v;
    zc[n] = (I == 0) ? 0.f : OMEGA * v / diagA<Nc,NCc>(sigc, I, J);
  }
}
// fused: prolong correction + one post-smooth (reads zin,zc; writes zout)
template<int N, int NC, int Nc>
__device__ void fpp(const float* sig, const float* f, const float* zin,
                    const float* zc, float* zout, int tid){
  for (int n = tid; n < N*N; n += NTHREADS){
    int i = n % N, j = n / N;
    if (i == 0){ zout[n] = 0.f; continue; }
    auto V = [&](int ii, int jj)->float{
      if (ii <= 0 || ii >= N || jj < 0 || jj >= N) return 0.f;
      return zin[jj*N+ii] + pval<Nc>(zc, ii, jj);
    };
    float vc = V(i,j);
    float Av = applyA_f<N,NC>(sig, V, i, j);
    zout[n] = vc + OMEGA * (f[n] - Av) / diagA<N,NC>(sig, i, j);
  }
}

__global__ __launch_bounds__(NTHREADS, 1)
void fem_mgcg_kernel(const float* __restrict__ mask, float* __restrict__ out){
  __shared__ float bufA[NNODE];          // fine pre-smooth z (descent) / final u
  __shared__ float bufB[NNODE];          // fine residual (descent) / final z (ascent)
  __shared__ float z1[48*48], f1[48*48], z1b[48*48];
  __shared__ float z2[24*24], f2[24*24], z2b[24*24];
  __shared__ float z3[12*12], f3[12*12], z3b[12*12];
  __shared__ float f4[6*6], z4[6*6], r4[6*6], d4a[6*6], d4b[6*6], zc4[6*6];
  __shared__ float sc1[47*47], sc2[23*23], sc3[11*11], sc4[5*5];
  __shared__ double pA[NWAVES], pB[NWAVES];

  const int tid = threadIdx.x, lane = tid & 63, wid = tid >> 6;
  const int bx = tid & 31, by = tid >> 5;
  const int i0 = 3*bx, j0 = 3*by;

  // ---- setup: fine sigma window in registers ----
  float S[4][4];
  #pragma unroll
  for (int a = 0; a < 4; a++)
    #pragma unroll
    for (int b = 0; b < 4; b++){
      int ci = i0-1+a, cj = j0-1+b;
      float m = 0.f;
      if (ci >= 0 && ci < NCW && cj >= 0 && cj < NCW)
        m = 0.001f + 0.999f * mask[cj*NCW + ci];
      S[a][b] = m;
    }
  float invd[3][3];
  #pragma unroll
  for (int di = 0; di < 3; di++)
    #pragma unroll
    for (int dj = 0; dj < 3; dj++){
      float cD = S[di+1][dj+1] + 3.f*S[di][dj+1] + S[di+1][dj] + S[di][dj];
      bool isbc = (i0+di == 0) || (i0+di == NXN-1);
      invd[di][dj] = isbc ? 0.f : 1.f/cD;
    }

  // ---- setup: coarse sigma hierarchies (4-cell averaging) ----
  for (int n = tid; n < 47*47; n += NTHREADS){
    int CI = n % 47, CJ = n / 47;
    float acc = 0.f;
    #pragma unroll
    for (int b = 0; b < 2; b++)
      #pragma unroll
      for (int a = 0; a < 2; a++)
        acc += 0.001f + 0.999f * mask[(2*CJ+b)*NCW + (2*CI+a)];
    sc1[n] = 0.25f * acc;
  }
  __syncthreads();
  for (int n = tid; n < 23*23; n += NTHREADS){
    int CI = n % 23, CJ = n / 23;
    sc2[n] = 0.25f*(sc1[(2*CJ)*47+2*CI]   + sc1[(2*CJ)*47+2*CI+1]
                  + sc1[(2*CJ+1)*47+2*CI] + sc1[(2*CJ+1)*47+2*CI+1]);
  }
  __syncthreads();
  for (int n = tid; n < 11*11; n += NTHREADS){
    int CI = n % 11, CJ = n / 11;
    sc3[n] = 0.25f*(sc2[(2*CJ)*23+2*CI]   + sc2[(2*CJ)*23+2*CI+1]
                  + sc2[(2*CJ+1)*23+2*CI] + sc2[(2*CJ+1)*23+2*CI+1]);
  }
  __syncthreads();
  for (int n = tid; n < 5*5; n += NTHREADS){
    int CI = n % 5, CJ = n / 5;
    sc4[n] = 0.25f*(sc3[(2*CJ)*11+2*CI]   + sc3[(2*CJ)*11+2*CI+1]
                  + sc3[(2*CJ+1)*11+2*CI] + sc3[(2*CJ+1)*11+2*CI+1]);
  }
  __syncthreads();

  // fine stencil on a 5x5 window (rows i==0,95 masked)
  #define STENCIL(Wm, di, dj, dst)                                          \
    {                                                                        \
      int i_ = i0+(di);                                                      \
      bool isbc_ = (i_ == 0) || (i_ == NXN-1);                               \
      float s00 = S[(di)+1][(dj)+1], sW = S[(di)][(dj)+1];                   \
      float sS  = S[(di)+1][(dj)],   sWS = S[(di)][(dj)];                    \
      float v_ = (s00 + 3.f*sW + sS + sWS)*Wm[(di)+1][(dj)+1]                \
               + 0.5f*(sS - s00)*Wm[(di)+2][(dj)+1]                          \
               + 0.5f*(sWS - sW)*Wm[(di)][(dj)+1]                            \
               - 0.5f*(s00 + 3.f*sW)*Wm[(di)+1][(dj)+2]                      \
               - 0.5f*(sS + 3.f*sWS)*Wm[(di)+1][(dj)]                        \
               - sW*Wm[(di)][(dj)+2]                                         \
               - sS*Wm[(di)+2][(dj)];                                        \
      dst = isbc_ ? 0.f : v_;                                                \
    }

  #define GATHER5x5(Wm, own, buf)                                           \
    _Pragma("unroll")                                                        \
    for (int a = 0; a < 5; a++)                                              \
      _Pragma("unroll")                                                      \
      for (int b = 0; b < 5; b++){                                           \
        if (a >= 1 && a <= 3 && b >= 1 && b <= 3){ Wm[a][b] = own[a-1][b-1]; continue; } \
        int gi = i0-1+a, gj = j0-1+b;                                        \
        Wm[a][b] = (gi >= 0 && gi < NXN && gj >= 0 && gj < NXN) ? buf[gj*NXN + gi] : 0.f; \
      }

  // Chebyshev(4) bottom-solve constants on [lmin, lmax] for D^-1 A
  const float CH_TH = (3.0f + 0.08f) * 0.5f;           // theta
  const float CH_DE = (3.0f - 0.08f) * 0.5f;           // delta
  const float CH_SG = CH_TH / CH_DE;                   // sigma
  const float RHO0 = 1.f/CH_SG;
  const float RHO1 = 1.f/(2.f*CH_SG - RHO0);
  const float RHO2 = 1.f/(2.f*CH_SG - RHO1);
  const float RHO3 = 1.f/(2.f*CH_SG - RHO2);
  const float A1 = RHO1*RHO0, B1 = 2.f*RHO1/CH_DE;
  const float A2 = RHO2*RHO1, B2 = 2.f*RHO2/CH_DE;
  const float A3 = RHO3*RHO2, B3 = 2.f*RHO3/CH_DE;

  // ---- warm start u0lin = 1 - i/95 ; r0 = -(A u0lin) on free rows ----
  float x[3][3], r[3][3], z[3][3], zp[3][3], w[3][3], p[3][3], s[3][3];
  #pragma unroll
  for (int di = 0; di < 3; di++)
    #pragma unroll
    for (int dj = 0; dj < 3; dj++){
      x[di][dj] = 0.f; p[di][dj] = 0.f; s[di][dj] = 0.f;
      int i = i0+di;
      float s00 = S[di+1][dj+1], sW = S[di][dj+1], sS = S[di+1][dj], sWS = S[di][dj];
      float uc = 1.f - (float)i     * (1.f/95.f);
      float uE = 1.f - (float)(i+1) * (1.f/95.f);
      float uW = 1.f - (float)(i-1) * (1.f/95.f);
      float v = (s00 + 3.f*sW + sS + sWS)*uc
              + 0.5f*(sS - s00)*uE + 0.5f*(sWS - sW)*uW
              - 0.5f*(s00 + 3.f*sW)*uc - 0.5f*(sS + 3.f*sWS)*uc
              - sW*uW - sS*uE;
      bool isbc = (i == 0) || (i == NXN-1);
      r[di][dj] = isbc ? 0.f : -v;
    }

  double gamma_old = 1.0, alpha_old = 1.0, gamma0 = 0.0;

  // ======== outer PCG (Chronopoulos-Gear) with fused MG V-cycle ====
  for (int it = 0; it < MAXIT_OUT; ++it){
    // P0: L0 pre-smooth (from zero) + publish to bufA
    #pragma unroll
    for (int di = 0; di < 3; di++)
      #pragma unroll
      for (int dj = 0; dj < 3; dj++){
        float zv = OMEGA * invd[di][dj] * r[di][dj];
        zp[di][dj] = zv;
        bufA[(j0+dj)*NXN + (i0+di)] = zv;
      }
    __syncthreads();
    // P1: fine residual -> bufB (own nodes, register sigma)
    {
      float Wm[5][5];
      GATHER5x5(Wm, zp, bufA);
      #pragma unroll
      for (int di = 0; di < 3; di++)
        #pragma unroll
        for (int dj = 0; dj < 3; dj++){
          float av; STENCIL(Wm, di, dj, av);
          int i = i0+di;
          bool isbc = (i == 0) || (i == NXN-1);
          bufB[(j0+dj)*NXN + i] = isbc ? 0.f : (r[di][dj] - av);
        }
    }
    __syncthreads();
    // P2: restrict 96->48 + smooth z1
    rrs0<96,48,47>(bufB, sc1, f1, z1, tid);
    __syncthreads();
    // P3: resid48+restrict->24 + smooth z2
    frrs<48,47,24,23>(sc1, f1, z1, sc2, f2, z2, tid);
    __syncthreads();
    // P4: resid24+restrict->12 + smooth z3
    frrs<24,23,12,11>(sc2, f2, z2, sc3, f3, z3, tid);
    __syncthreads();
    // P5: resid12+restrict->6 + Chebyshev init (d0 = (1/theta) D^-1 f4; z=d0)
    for (int n = tid; n < 36; n += NTHREADS){
      int I = n % 6, J = n / 6;
      float v = 0.f;
      if (I != 0){
        auto RS = [&](int i, int j)->float{
          if (i <= 0 || i >= 12 || j < 0 || j >= 12) return 0.f;
          return f3[j*12+i] - applyA<12,11>(sc3, z3, i, j);
        };
        int fi = 2*I, fj = 2*J;
        v = RS(fi,fj)
          + 0.5f*( RS(fi+1,fj) + RS(fi-1,fj) + RS(fi,fj+1) + RS(fi,fj-1)
                 + RS(fi+1,fj-1) + RS(fi-1,fj+1) );
      }
      f4[n] = v;
      float d0 = (I == 0) ? 0.f : (1.f/CH_TH) * v / diagA<6,5>(sc4, I, J);
      d4a[n] = d0; z4[n] = d0;
    }
    __syncthreads();
    // P6: cheb k=1
    for (int n = tid; n < 36; n += NTHREADS){
      int I = n % 6, J = n / 6;
      if (I == 0){ r4[n] = 0.f; d4b[n] = 0.f; continue; }
      float rn = f4[n] - applyA<6,5>(sc4, d4a, I, J);
      r4[n] = rn;
      float dn = A1*d4a[n] + B1*(rn / diagA<6,5>(sc4, I, J));
      d4b[n] = dn; z4[n] += dn;
    }
    __syncthreads();
    // P7: cheb k=2
    for (int n = tid; n < 36; n += NTHREADS){
      int I = n % 6, J = n / 6;
      if (I == 0){ d4a[n] = 0.f; continue; }
      float rn = r4[n] - applyA<6,5>(sc4, d4b, I, J);
      r4[n] = rn;
      float dn = A2*d4b[n] + B2*(rn / diagA<6,5>(sc4, I, J));
      d4a[n] = dn; z4[n] += dn;
    }
    __syncthreads();
    // P8: cheb k=3 (final) -> zc4
    for (int n = tid; n < 36; n += NTHREADS){
      int I = n % 6, J = n / 6;
      if (I == 0){ zc4[n] = 0.f; continue; }
      float rn = r4[n] - applyA<6,5>(sc4, d4a, I, J);
      float dn = A3*d4a[n] + B3*(rn / diagA<6,5>(sc4, I, J));
      zc4[n] = z4[n] + dn;
    }
    __syncthreads();
    // P9..P11: ascent, fused prolong+post-smooth
    fpp<12,11,6>(sc3, f3, z3, zc4, z3b, tid);  __syncthreads();
    fpp<24,23,12>(sc2, f2, z2, z3b, z2b, tid); __syncthreads();
    fpp<48,47,24>(sc1, f1, z1, z2b, z1b, tid); __syncthreads();
    // P12: L0 fused prolong + post-smooth -> z regs, publish bufB
    {
      float Vw[5][5];
      #pragma unroll
      for (int a = 0; a < 5; a++)
        #pragma unroll
        for (int b = 0; b < 5; b++){
          int gi = i0-1+a, gj = j0-1+b;
          float val = 0.f;
          if (gi > 0 && gi < NXN-1 && gj >= 0 && gj < NXN)
            val = bufA[gj*NXN + gi] + pval<48>(z1b, gi, gj);
          Vw[a][b] = val;
        }
      #pragma unroll
      for (int di = 0; di < 3; di++)
        #pragma unroll
        for (int dj = 0; dj < 3; dj++){
          float av; STENCIL(Vw, di, dj, av);
          float zn = Vw[di+1][dj+1] + OMEGA * invd[di][dj] * (r[di][dj] - av);
          z[di][dj] = zn;
          bufB[(j0+dj)*NXN + (i0+di)] = zn;
        }
    }
    __syncthreads();
    // P13: outer matvec w = A z ; dots gamma = r.z, delta = w.z
    double gp = 0.0, dp = 0.0;
    {
      float Wm[5][5];
      GATHER5x5(Wm, z, bufB);
      #pragma unroll
      for (int di = 0; di < 3; di++)
        #pragma unroll
        for (int dj = 0; dj < 3; dj++){
          float av; STENCIL(Wm, di, dj, av);
          w[di][dj] = av;
          gp += (double)r[di][dj] * (double)z[di][dj];
          dp += (double)av        * (double)z[di][dj];
        }
    }
    dual_warp_red(gp, dp);
    if (lane == 0){ pA[wid] = gp; pB[wid] = dp; }
    __syncthreads();
    double gamma = sum16_tree(pA);
    double delta = sum16_tree(pB);
    if (it == 0) gamma0 = gamma;
    if (gamma <= gamma0 * 1e-9 || !(delta > 0.0)) break;   // safety floor

    double beta  = (it == 0) ? 0.0 : gamma / gamma_old;
    double alpha = (it == 0) ? gamma / delta
                             : gamma / (delta - beta * gamma / alpha_old);
    gamma_old = gamma; alpha_old = alpha;
    float bf = (float)beta, af = (float)alpha;

    #pragma unroll
    for (int di = 0; di < 3; di++)
      #pragma unroll
      for (int dj = 0; dj < 3; dj++){
        float pn = z[di][dj] + bf * p[di][dj];  p[di][dj] = pn;
        float sn = w[di][dj] + bf * s[di][dj];  s[di][dj] = sn;
        x[di][dj] += af * pn;
        r[di][dj] -= af * sn;
      }

    if (alpha * gamma <= ATOL_E) break;   // energy-error tail bound
  }

  __syncthreads();
  // ---- final u = u0lin + x into bufA ----
  #pragma unroll
  for (int di = 0; di < 3; di++)
    #pragma unroll
    for (int dj = 0; dj < 3; dj++){
      int i = i0+di, j = j0+dj;
      float u;
      if (i == 0) u = 1.f;
      else if (i == NXN-1) u = 0.f;
      else u = 1.f - (float)i*(1.f/95.f) + x[di][dj];
      bufA[j*NXN + i] = u;
    }
  __syncthreads();

  // ---- energy ----
  float U[4][4];
  #pragma unroll
  for (int a = 0; a < 4; a++)
    #pragma unroll
    for (int b = 0; b < 4; b++){
      int gi = i0+a, gj = j0+b;
      U[a][b] = (gi < NXN && gj < NXN) ? bufA[gj*NXN + gi] : 0.f;
    }
  double ep = 0.0;
  #pragma unroll
  for (int di = 0; di < 3; di++)
    #pragma unroll
    for (int dj = 0; dj < 3; dj++){
      int ci = i0+di, cj = j0+dj;
      if (ci < NCW && cj < NCW){
        float sig = S[di+1][dj+1];
        float u00 = U[di][dj], uE = U[di+1][dj], uN = U[di][dj+1], uNE = U[di+1][dj+1];
        float gxA = uE - u00, gyA = uN - u00;
        float gxB = -2.f*uE + uNE + uN, gyB = uE - uNE;
        ep += (double)(sig * 0.5f * (gxA*gxA + gyA*gyA + gxB*gxB + gyB*gyB));
      }
    }
  {
    double dummy = 0.0;
    dual_warp_red(ep, dummy);
    if (lane == 0) pA[wid] = ep;
  }
  __syncthreads();
  if (tid == 0) out[0] = (float)sum16_tree(pA);
}

extern "C" void kernel_launch(void* const* d_in, const int* in_sizes, int n_in,
                              void* d_out, int out_size, void* d_ws, size_t ws_size,
                              hipStream_t stream){
  (void)d_ws; (void)ws_size; (void)out_size;
  int mi = 0;
  for (int k = 0; k < n_in; k++) if (in_sizes[k] == 9025) { mi = k; break; }
  const float* mask = (const float*)d_in[mi];
  fem_mgcg_kernel<<<dim3(1), dim3(NTHREADS), 0, stream>>>(mask, (float*)d_out);
}

// Round 9
// 365.220 us; speedup vs baseline: 2.3187x; 2.3187x over previous
//
#include <hip/hip_runtime.h>

#define NXN 96
#define NNODE (NXN*NXN)
#define NCW 95
#define NTHREADS 1024
#define NWAVES (NTHREADS/64)
#define MAXIT_OUT 300
#define ATOL_E 6e-4       // absolute tail bound on alpha*gamma
#define OMEGA 0.6f

__device__ __forceinline__ void dual_warp_red(double& a, double& b){
  #pragma unroll
  for (int off = 32; off > 0; off >>= 1){
    a += __shfl_down(a, off, 64);
    b += __shfl_down(b, off, 64);
  }
}

__device__ __forceinline__ double sum16_tree(const double* buf){
  double t0 = buf[0]  + buf[1],  t1 = buf[2]  + buf[3];
  double t2 = buf[4]  + buf[5],  t3 = buf[6]  + buf[7];
  double t4 = buf[8]  + buf[9],  t5 = buf[10] + buf[11];
  double t6 = buf[12] + buf[13], t7 = buf[14] + buf[15];
  double u0 = t0 + t1, u1 = t2 + t3, u2 = t4 + t5, u3 = t6 + t7;
  return (u0 + u1) + (u2 + u3);
}

// ---- level helpers (coarse levels: Dirichlet at i==0 only) ----
template<int N, int NC>
__device__ __forceinline__ float sgf(const float* sig, int ci, int cj){
  return (ci >= 0 && ci < NC && cj >= 0 && cj < NC) ? sig[cj*NC + ci] : 0.f;
}
template<int N>
__device__ __forceinline__ float vf(const float* v, int i, int j){
  return (i >= 0 && i < N && j >= 0 && j < N) ? v[j*N + i] : 0.f;
}
template<int N, int NC>
__device__ __forceinline__ float diagA(const float* sig, int i, int j){
  float s00 = sgf<N,NC>(sig,i,j),   sW  = sgf<N,NC>(sig,i-1,j);
  float sS  = sgf<N,NC>(sig,i,j-1), sWS = sgf<N,NC>(sig,i-1,j-1);
  return s00 + 3.f*sW + sS + sWS;
}
template<int N, int NC>
__device__ __forceinline__ float applyA(const float* sig, const float* v, int i, int j){
  float s00 = sgf<N,NC>(sig,i,j),   sW  = sgf<N,NC>(sig,i-1,j);
  float sS  = sgf<N,NC>(sig,i,j-1), sWS = sgf<N,NC>(sig,i-1,j-1);
  return (s00 + 3.f*sW + sS + sWS)*vf<N>(v,i,j)
       + 0.5f*(sS  - s00)*vf<N>(v,i+1,j)
       + 0.5f*(sWS - sW )*vf<N>(v,i-1,j)
       - 0.5f*(s00 + 3.f*sW )*vf<N>(v,i,j+1)
       - 0.5f*(sS  + 3.f*sWS)*vf<N>(v,i,j-1)
       - sW*vf<N>(v,i-1,j+1)
       - sS*vf<N>(v,i+1,j-1);
}
// residual (own level, full parallelism, light)
template<int N, int NC>
__device__ void residual_lvl(const float* sig, const float* f, const float* z, float* dout, int tid){
  for (int n = tid; n < N*N; n += NTHREADS){
    int i = n % N, j = n / N;
    dout[n] = (i == 0) ? 0.f : f[n] - applyA<N,NC>(sig,z,i,j);
  }
}
// fused restrict + smooth-from-zero (reads PRECOMPUTED fine residual; light)
template<int Nf, int Nc, int NCc>
__device__ void rrs0(const float* dfine, const float* sigc, float* fc, float* zc, int tid){
  for (int n = tid; n < Nc*Nc; n += NTHREADS){
    int I = n % Nc, J = n / Nc;
    float v = 0.f;
    if (I != 0){
      int fi = 2*I, fj = 2*J;
      v = vf<Nf>(dfine,fi,fj)
        + 0.5f*( vf<Nf>(dfine,fi+1,fj) + vf<Nf>(dfine,fi-1,fj)
               + vf<Nf>(dfine,fi,fj+1) + vf<Nf>(dfine,fi,fj-1)
               + vf<Nf>(dfine,fi+1,fj-1) + vf<Nf>(dfine,fi-1,fj+1) );
    }
    fc[n] = v;
    zc[n] = (I == 0) ? 0.f : OMEGA * v / diagA<Nc,NCc>(sigc, I, J);
  }
}
template<int Nf, int Nc>
__device__ void prolong_add(const float* zc, float* zfine, int tid){
  for (int n = tid; n < Nf*Nf; n += NTHREADS){
    int i = n % Nf, j = n / Nf;
    if (i == 0) continue;
    int ie = i & 1, je = j & 1;
    float add;
    if (!ie && !je)      add = vf<Nc>(zc, i>>1, j>>1);
    else if (ie && !je)  add = 0.5f*(vf<Nc>(zc,(i-1)>>1, j>>1) + vf<Nc>(zc,(i+1)>>1, j>>1));
    else if (!ie && je)  add = 0.5f*(vf<Nc>(zc, i>>1, (j-1)>>1) + vf<Nc>(zc, i>>1, (j+1)>>1));
    else                 add = 0.5f*(vf<Nc>(zc,(i+1)>>1,(j-1)>>1) + vf<Nc>(zc,(i-1)>>1,(j+1)>>1));
    zfine[n] += add;
  }
}
// post-smooth, double-buffered
template<int N, int NC>
__device__ void post_smooth_db(const float* sig, const float* f, const float* zin, float* zout, int tid){
  for (int n = tid; n < N*N; n += NTHREADS){
    int i = n % N, j = n / N;
    zout[n] = (i == 0) ? 0.f
            : zin[n] + OMEGA * (f[n] - applyA<N,NC>(sig,zin,i,j)) / diagA<N,NC>(sig,i,j);
  }
}

__global__ __launch_bounds__(NTHREADS, 1)
void fem_mgcg_kernel(const float* __restrict__ mask, float* __restrict__ out){
  __shared__ float bufA[NNODE];          // fine z publish / final u
  __shared__ float bufB[NNODE];          // fine residual
  __shared__ float z1[48*48], f1[48*48], z1b[48*48];
  __shared__ float z2[24*24], f2[24*24], z2b[24*24];
  __shared__ float z3[12*12], f3[12*12], z3b[12*12];
  __shared__ float f4[6*6], z4[6*6], r4[6*6], d4a[6*6], d4b[6*6], zc4[6*6];
  __shared__ float sc1[47*47], sc2[23*23], sc3[11*11], sc4[5*5];
  __shared__ float dscratch[48*48];
  __shared__ double pA[NWAVES], pB[NWAVES];

  const int tid = threadIdx.x, lane = tid & 63, wid = tid >> 6;
  const int bx = tid & 31, by = tid >> 5;
  const int i0 = 3*bx, j0 = 3*by;

  // ---- setup: fine sigma window in registers ----
  float S[4][4];
  #pragma unroll
  for (int a = 0; a < 4; a++)
    #pragma unroll
    for (int b = 0; b < 4; b++){
      int ci = i0-1+a, cj = j0-1+b;
      float m = 0.f;
      if (ci >= 0 && ci < NCW && cj >= 0 && cj < NCW)
        m = 0.001f + 0.999f * mask[cj*NCW + ci];
      S[a][b] = m;
    }
  float invd[3][3];
  #pragma unroll
  for (int di = 0; di < 3; di++)
    #pragma unroll
    for (int dj = 0; dj < 3; dj++){
      float cD = S[di+1][dj+1] + 3.f*S[di][dj+1] + S[di+1][dj] + S[di][dj];
      bool isbc = (i0+di == 0) || (i0+di == NXN-1);
      invd[di][dj] = isbc ? 0.f : 1.f/cD;
    }

  // ---- setup: coarse sigma hierarchies (4-cell averaging) ----
  for (int n = tid; n < 47*47; n += NTHREADS){
    int CI = n % 47, CJ = n / 47;
    float acc = 0.f;
    #pragma unroll
    for (int b = 0; b < 2; b++)
      #pragma unroll
      for (int a = 0; a < 2; a++)
        acc += 0.001f + 0.999f * mask[(2*CJ+b)*NCW + (2*CI+a)];
    sc1[n] = 0.25f * acc;
  }
  __syncthreads();
  for (int n = tid; n < 23*23; n += NTHREADS){
    int CI = n % 23, CJ = n / 23;
    sc2[n] = 0.25f*(sc1[(2*CJ)*47+2*CI]   + sc1[(2*CJ)*47+2*CI+1]
                  + sc1[(2*CJ+1)*47+2*CI] + sc1[(2*CJ+1)*47+2*CI+1]);
  }
  __syncthreads();
  for (int n = tid; n < 11*11; n += NTHREADS){
    int CI = n % 11, CJ = n / 11;
    sc3[n] = 0.25f*(sc2[(2*CJ)*23+2*CI]   + sc2[(2*CJ)*23+2*CI+1]
                  + sc2[(2*CJ+1)*23+2*CI] + sc2[(2*CJ+1)*23+2*CI+1]);
  }
  __syncthreads();
  for (int n = tid; n < 5*5; n += NTHREADS){
    int CI = n % 5, CJ = n / 5;
    sc4[n] = 0.25f*(sc3[(2*CJ)*11+2*CI]   + sc3[(2*CJ)*11+2*CI+1]
                  + sc3[(2*CJ+1)*11+2*CI] + sc3[(2*CJ+1)*11+2*CI+1]);
  }
  __syncthreads();

  // fine stencil on a 5x5 window (rows i==0,95 masked)
  #define STENCIL(Wm, di, dj, dst)                                          \
    {                                                                        \
      int i_ = i0+(di);                                                      \
      bool isbc_ = (i_ == 0) || (i_ == NXN-1);                               \
      float s00 = S[(di)+1][(dj)+1], sW = S[(di)][(dj)+1];                   \
      float sS  = S[(di)+1][(dj)],   sWS = S[(di)][(dj)];                    \
      float v_ = (s00 + 3.f*sW + sS + sWS)*Wm[(di)+1][(dj)+1]                \
               + 0.5f*(sS - s00)*Wm[(di)+2][(dj)+1]                          \
               + 0.5f*(sWS - sW)*Wm[(di)][(dj)+1]                            \
               - 0.5f*(s00 + 3.f*sW)*Wm[(di)+1][(dj)+2]                      \
               - 0.5f*(sS + 3.f*sWS)*Wm[(di)+1][(dj)]                        \
               - sW*Wm[(di)][(dj)+2]                                         \
               - sS*Wm[(di)+2][(dj)];                                        \
      dst = isbc_ ? 0.f : v_;                                                \
    }

  #define GATHER5x5(Wm, own, buf)                                           \
    _Pragma("unroll")                                                        \
    for (int a = 0; a < 5; a++)                                              \
      _Pragma("unroll")                                                      \
      for (int b = 0; b < 5; b++){                                           \
        if (a >= 1 && a <= 3 && b >= 1 && b <= 3){ Wm[a][b] = own[a-1][b-1]; continue; } \
        int gi = i0-1+a, gj = j0-1+b;                                        \
        Wm[a][b] = (gi >= 0 && gi < NXN && gj >= 0 && gj < NXN) ? buf[gj*NXN + gi] : 0.f; \
      }

  // Chebyshev(4) bottom-solve constants on [lmin, lmax] for D^-1 A
  const float CH_TH = (3.0f + 0.08f) * 0.5f;           // theta
  const float CH_DE = (3.0f - 0.08f) * 0.5f;           // delta
  const float CH_SG = CH_TH / CH_DE;                   // sigma
  const float RHO0 = 1.f/CH_SG;
  const float RHO1 = 1.f/(2.f*CH_SG - RHO0);
  const float RHO2 = 1.f/(2.f*CH_SG - RHO1);
  const float RHO3 = 1.f/(2.f*CH_SG - RHO2);
  const float A1 = RHO1*RHO0, B1 = 2.f*RHO1/CH_DE;
  const float A2 = RHO2*RHO1, B2 = 2.f*RHO2/CH_DE;
  const float A3 = RHO3*RHO2, B3 = 2.f*RHO3/CH_DE;

  // ---- warm start u0lin = 1 - i/95 ; r0 = -(A u0lin) on free rows ----
  float x[3][3], r[3][3], z0[3][3], w[3][3], p[3][3], s[3][3];
  #pragma unroll
  for (int di = 0; di < 3; di++)
    #pragma unroll
    for (int dj = 0; dj < 3; dj++){
      x[di][dj] = 0.f; p[di][dj] = 0.f; s[di][dj] = 0.f;
      int i = i0+di;
      float s00 = S[di+1][dj+1], sW = S[di][dj+1], sS = S[di+1][dj], sWS = S[di][dj];
      float uc = 1.f - (float)i     * (1.f/95.f);
      float uE = 1.f - (float)(i+1) * (1.f/95.f);
      float uW = 1.f - (float)(i-1) * (1.f/95.f);
      float v = (s00 + 3.f*sW + sS + sWS)*uc
              + 0.5f*(sS - s00)*uE + 0.5f*(sWS - sW)*uW
              - 0.5f*(s00 + 3.f*sW)*uc - 0.5f*(sS + 3.f*sWS)*uc
              - sW*uW - sS*uE;
      bool isbc = (i == 0) || (i == NXN-1);
      r[di][dj] = isbc ? 0.f : -v;
    }

  double gamma_old = 1.0, alpha_old = 1.0, gamma0 = 0.0;

  // ======== outer PCG (Chronopoulos-Gear) with MG V-cycle (Cheb bottom) ====
  for (int it = 0; it < MAXIT_OUT; ++it){
    // P0: L0 pre-smooth (from zero) + publish to bufA
    #pragma unroll
    for (int di = 0; di < 3; di++)
      #pragma unroll
      for (int dj = 0; dj < 3; dj++){
        float zv = OMEGA * invd[di][dj] * r[di][dj];
        z0[di][dj] = zv;
        bufA[(j0+dj)*NXN + (i0+di)] = zv;
      }
    __syncthreads();
    // P1: fine residual -> bufB
    {
      float Wm[5][5];
      GATHER5x5(Wm, z0, bufA);
      #pragma unroll
      for (int di = 0; di < 3; di++)
        #pragma unroll
        for (int dj = 0; dj < 3; dj++){
          float av; STENCIL(Wm, di, dj, av);
          int i = i0+di;
          bool isbc = (i == 0) || (i == NXN-1);
          bufB[(j0+dj)*NXN + i] = isbc ? 0.f : (r[di][dj] - av);
        }
    }
    __syncthreads();
    // descent: residual (full-parallel) + fused restrict+smooth
    rrs0<96,48,47>(bufB, sc1, f1, z1, tid);              __syncthreads();
    residual_lvl<48,47>(sc1, f1, z1, dscratch, tid);     __syncthreads();
    rrs0<48,24,23>(dscratch, sc2, f2, z2, tid);          __syncthreads();
    residual_lvl<24,23>(sc2, f2, z2, dscratch, tid);     __syncthreads();
    rrs0<24,12,11>(dscratch, sc3, f3, z3, tid);          __syncthreads();
    residual_lvl<12,11>(sc3, f3, z3, dscratch, tid);     __syncthreads();
    // bottom init: restrict 12->6 + Chebyshev d0
    for (int n = tid; n < 36; n += NTHREADS){
      int I = n % 6, J = n / 6;
      float v = 0.f;
      if (I != 0){
        int fi = 2*I, fj = 2*J;
        v = vf<12>(dscratch,fi,fj)
          + 0.5f*( vf<12>(dscratch,fi+1,fj) + vf<12>(dscratch,fi-1,fj)
                 + vf<12>(dscratch,fi,fj+1) + vf<12>(dscratch,fi,fj-1)
                 + vf<12>(dscratch,fi+1,fj-1) + vf<12>(dscratch,fi-1,fj+1) );
      }
      f4[n] = v;
      float d0 = (I == 0) ? 0.f : (1.f/CH_TH) * v / diagA<6,5>(sc4, I, J);
      d4a[n] = d0; z4[n] = d0;
    }
    __syncthreads();
    // cheb k=1
    for (int n = tid; n < 36; n += NTHREADS){
      int I = n % 6, J = n / 6;
      if (I == 0){ r4[n] = 0.f; d4b[n] = 0.f; continue; }
      float rn = f4[n] - applyA<6,5>(sc4, d4a, I, J);
      r4[n] = rn;
      float dn = A1*d4a[n] + B1*(rn / diagA<6,5>(sc4, I, J));
      d4b[n] = dn; z4[n] += dn;
    }
    __syncthreads();
    // cheb k=2
    for (int n = tid; n < 36; n += NTHREADS){
      int I = n % 6, J = n / 6;
      if (I == 0){ d4a[n] = 0.f; continue; }
      float rn = r4[n] - applyA<6,5>(sc4, d4b, I, J);
      r4[n] = rn;
      float dn = A2*d4b[n] + B2*(rn / diagA<6,5>(sc4, I, J));
      d4a[n] = dn; z4[n] += dn;
    }
    __syncthreads();
    // cheb k=3 (final) -> zc4
    for (int n = tid; n < 36; n += NTHREADS){
      int I = n % 6, J = n / 6;
      if (I == 0){ zc4[n] = 0.f; continue; }
      float rn = r4[n] - applyA<6,5>(sc4, d4a, I, J);
      float dn = A3*d4a[n] + B3*(rn / diagA<6,5>(sc4, I, J));
      zc4[n] = z4[n] + dn;
    }
    __syncthreads();
    // ascent: prolong + double-buffered post-smooth (R6-proven)
    prolong_add<12,6>(zc4, z3, tid);                 __syncthreads();
    post_smooth_db<12,11>(sc3, f3, z3, z3b, tid);    __syncthreads();
    prolong_add<24,12>(z3b, z2, tid);                __syncthreads();
    post_smooth_db<24,23>(sc2, f2, z2, z2b, tid);    __syncthreads();
    prolong_add<48,24>(z2b, z1, tid);                __syncthreads();
    post_smooth_db<48,47>(sc1, f1, z1, z1b, tid);    __syncthreads();
    // L0 prolong from z1b into registers (mask BC rows)
    #pragma unroll
    for (int di = 0; di < 3; di++)
      #pragma unroll
      for (int dj = 0; dj < 3; dj++){
        int i = i0+di, j = j0+dj;
        if (i == 0 || i == NXN-1) continue;
        int ie = i & 1, je = j & 1;
        float add;
        if (!ie && !je)      add = vf<48>(z1b, i>>1, j>>1);
        else if (ie && !je)  add = 0.5f*(vf<48>(z1b,(i-1)>>1, j>>1) + vf<48>(z1b,(i+1)>>1, j>>1));
        else if (!ie && je)  add = 0.5f*(vf<48>(z1b, i>>1, (j-1)>>1) + vf<48>(z1b, i>>1, (j+1)>>1));
        else                 add = 0.5f*(vf<48>(z1b,(i+1)>>1,(j-1)>>1) + vf<48>(z1b,(i-1)>>1,(j+1)>>1));
        z0[di][dj] += add;
      }
    // publish, post-smooth L0
    #pragma unroll
    for (int di = 0; di < 3; di++)
      #pragma unroll
      for (int dj = 0; dj < 3; dj++)
        bufA[(j0+dj)*NXN + (i0+di)] = z0[di][dj];
    __syncthreads();
    {
      float Wm[5][5];
      GATHER5x5(Wm, z0, bufA);
      #pragma unroll
      for (int di = 0; di < 3; di++)
        #pragma unroll
        for (int dj = 0; dj < 3; dj++){
          float av; STENCIL(Wm, di, dj, av);
          z0[di][dj] += OMEGA * invd[di][dj] * (r[di][dj] - av);
        }
    }
    __syncthreads();   // all reads of bufA done before republish
    #pragma unroll
    for (int di = 0; di < 3; di++)
      #pragma unroll
      for (int dj = 0; dj < 3; dj++)
        bufA[(j0+dj)*NXN + (i0+di)] = z0[di][dj];
    __syncthreads();

    // ---- outer matvec w = A z ; dots gamma = r.z, delta = w.z ----
    double gp = 0.0, dp = 0.0;
    {
      float Wm[5][5];
      GATHER5x5(Wm, z0, bufA);
      #pragma unroll
      for (int di = 0; di < 3; di++)
        #pragma unroll
        for (int dj = 0; dj < 3; dj++){
          float av; STENCIL(Wm, di, dj, av);
          w[di][dj] = av;
          gp += (double)r[di][dj] * (double)z0[di][dj];
          dp += (double)av        * (double)z0[di][dj];
        }
    }
    dual_warp_red(gp, dp);
    if (lane == 0){ pA[wid] = gp; pB[wid] = dp; }
    __syncthreads();
    double gamma = sum16_tree(pA);
    double delta = sum16_tree(pB);
    if (it == 0) gamma0 = gamma;
    if (gamma <= gamma0 * 1e-9 || !(delta > 0.0)) break;   // safety floor

    double beta  = (it == 0) ? 0.0 : gamma / gamma_old;
    double alpha = (it == 0) ? gamma / delta
                             : gamma / (delta - beta * gamma / alpha_old);
    gamma_old = gamma; alpha_old = alpha;
    float bf = (float)beta, af = (float)alpha;

    #pragma unroll
    for (int di = 0; di < 3; di++)
      #pragma unroll
      for (int dj = 0; dj < 3; dj++){
        float pn = z0[di][dj] + bf * p[di][dj];  p[di][dj] = pn;
        float sn = w[di][dj]  + bf * s[di][dj];  s[di][dj] = sn;
        x[di][dj] += af * pn;
        r[di][dj] -= af * sn;
      }

    if (alpha * gamma <= ATOL_E) break;   // energy-error tail bound
  }

  __syncthreads();
  // ---- final u = u0lin + x into bufA ----
  #pragma unroll
  for (int di = 0; di < 3; di++)
    #pragma unroll
    for (int dj = 0; dj < 3; dj++){
      int i = i0+di, j = j0+dj;
      float u;
      if (i == 0) u = 1.f;
      else if (i == NXN-1) u = 0.f;
      else u = 1.f - (float)i*(1.f/95.f) + x[di][dj];
      bufA[j*NXN + i] = u;
    }
  __syncthreads();

  // ---- energy ----
  float U[4][4];
  #pragma unroll
  for (int a = 0; a < 4; a++)
    #pragma unroll
    for (int b = 0; b < 4; b++){
      int gi = i0+a, gj = j0+b;
      U[a][b] = (gi < NXN && gj < NXN) ? bufA[gj*NXN + gi] : 0.f;
    }
  double ep = 0.0;
  #pragma unroll
  for (int di = 0; di < 3; di++)
    #pragma unroll
    for (int dj = 0; dj < 3; dj++){
      int ci = i0+di, cj = j0+dj;
      if (ci < NCW && cj < NCW){
        float sig = S[di+1][dj+1];
        float u00 = U[di][dj], uE = U[di+1][dj], uN = U[di][dj+1], uNE = U[di+1][dj+1];
        float gxA = uE - u00, gyA = uN - u00;
        float gxB = -2.f*uE + uNE + uN, gyB = uE - uNE;
        ep += (double)(sig * 0.5f * (gxA*gxA + gyA*gyA + gxB*gxB + gyB*gyB));
      }
    }
  {
    double dummy = 0.0;
    dual_warp_red(ep, dummy);
    if (lane == 0) pA[wid] = ep;
  }
  __syncthreads();
  if (tid == 0) out[0] = (float)sum16_tree(pA);
}

extern "C" void kernel_launch(void* const* d_in, const int* in_sizes, int n_in,
                              void* d_out, int out_size, void* d_ws, size_t ws_size,
                              hipStream_t stream){
  (void)d_ws; (void)ws_size; (void)out_size;
  int mi = 0;
  for (int k = 0; k < n_in; k++) if (in_sizes[k] == 9025) { mi = k; break; }
  const float* mask = (const float*)d_in[mi];
  fem_mgcg_kernel<<<dim3(1), dim3(NTHREADS), 0, stream>>>(mask, (float*)d_out);
}